// Round 6
// baseline (144.138 us; speedup 1.0000x reference)
//
#include <hip/hip_runtime.h>
#include <math.h>

#define NTOK 2304      // 48*48 tokens
#define BATCH 2
#define CIN 256
#define HID 512        // 8 heads * 64
#define NH 8
#define LOG2E 1.44269504088896340736f

typedef __attribute__((ext_vector_type(8))) short bfrag;    // 8 bf16 (4 VGPRs)
typedef __attribute__((ext_vector_type(16))) float f32x16;  // MFMA 32x32 accumulator

#if __has_builtin(__builtin_amdgcn_exp2f)
#define EXP2(x) __builtin_amdgcn_exp2f(x)
#else
#define EXP2(x) exp2f(x)
#endif

// fp32 -> bf16 (RNE)
__device__ __forceinline__ unsigned f2bf(float f) {
    unsigned u = __float_as_uint(f);
    u += 0x7FFF + ((u >> 16) & 1);
    return u >> 16;
}

// pack trunc(hi(b)) , trunc(hi(a)) -> one dword {bf16(b):bf16(a)} in 1 v_perm
__device__ __forceinline__ unsigned pk_trunc(float a, float b) {
    return __builtin_amdgcn_perm(__float_as_uint(b), __float_as_uint(a), 0x07060302u);
}

// exp2 + bf16-pack + lane^32 half-swap: accS (S^T quadrant, C-layout) ->
// two A-operand P frags; accumulates this lane's partial row sums.
// Row-sum uses a tree (depth 4) instead of a 16-deep serial add chain.
__device__ __forceinline__ void softmax_frag(
    const f32x16& accS, int h, float& ps0, float& ps1, bfrag& P0, bfrag& P1)
{
    unsigned dw[8];
    float e0[8], e1[8];
#pragma unroll
    for (int i = 0; i < 8; i++) {
        float plo = EXP2(accS[2 * i]);
        float phi = EXP2(accS[2 * i + 1]);
        dw[i] = pk_trunc(plo, phi);
        e0[i] = __uint_as_float(dw[i] << 16);
        e1[i] = __uint_as_float(dw[i] & 0xffff0000u);
    }
    ps0 += ((e0[0] + e0[1]) + (e0[2] + e0[3])) + ((e0[4] + e0[5]) + (e0[6] + e0[7]));
    ps1 += ((e1[0] + e1[1]) + (e1[2] + e1[3])) + ((e1[4] + e1[5]) + (e1[6] + e1[7]));
    unsigned sa0 = h ? dw[0] : dw[2], sb0 = h ? dw[1] : dw[3];
    unsigned sa1 = h ? dw[4] : dw[6], sb1 = h ? dw[5] : dw[7];
    unsigned ra0 = (unsigned)__shfl_xor((int)sa0, 32, 64);
    unsigned rb0 = (unsigned)__shfl_xor((int)sb0, 32, 64);
    unsigned ra1 = (unsigned)__shfl_xor((int)sa1, 32, 64);
    unsigned rb1 = (unsigned)__shfl_xor((int)sb1, 32, 64);
    union { bfrag f; unsigned u[4]; } U0, U1;
    U0.u[0] = h ? ra0 : dw[0];  U0.u[1] = h ? rb0 : dw[1];
    U0.u[2] = h ? dw[2] : ra0;  U0.u[3] = h ? dw[3] : rb0;
    U1.u[0] = h ? ra1 : dw[4];  U1.u[1] = h ? rb1 : dw[5];
    U1.u[2] = h ? dw[6] : ra1;  U1.u[3] = h ? dw[7] : rb1;
    P0 = U0.f; P1 = U1.f;
}

// ---------------------------------------------------------------------------
// Pack both weight matrices fp32 -> bf16 FRAGMENT-MAJOR in one dispatch.
//   wqb: [ob=48][kc=16][lane=64][8]  value = Wq[ob*32+(lane&31)][kc*16+(lane>>5)*8+e]
//   wpb: [ob=8][kc=32][lane=64][8]   value = Wp[ob*32+(lane&31)][kc*16+(lane>>5)*8+e]
// ---------------------------------------------------------------------------
__global__ __launch_bounds__(256) void pack_weights(
    const float* __restrict__ wq, short* __restrict__ wqb,
    const float* __restrict__ wp, short* __restrict__ wpb)
{
    int e = (blockIdx.x * 256 + threadIdx.x) * 8;
    const int NQ = 1536 * 256;
    const float* src; short* dst;
    if (e < NQ) {
        int row = e >> 8, c = e & 255;
        int off = (((row >> 5) * 16 + (c >> 4)) * 64 + ((c >> 3) & 1) * 32 + (row & 31)) * 8;
        src = wq + e; dst = wqb + off;
    } else {
        int e2 = e - NQ;
        int row = e2 >> 9, c = e2 & 511;
        int off = (((row >> 5) * 32 + (c >> 4)) * 64 + ((c >> 3) & 1) * 32 + (row & 31)) * 8;
        src = wp + e2; dst = wpb + off;
    }
    float4 v0 = ((const float4*)src)[0];
    float4 v1 = ((const float4*)src)[1];
    unsigned b0 = f2bf(v0.x) | (f2bf(v0.y) << 16);
    unsigned b1 = f2bf(v0.z) | (f2bf(v0.w) << 16);
    unsigned b2 = f2bf(v1.x) | (f2bf(v1.y) << 16);
    unsigned b3 = f2bf(v1.z) | (f2bf(v1.w) << 16);
    *((uint4*)dst) = make_uint4(b0, b1, b2, b3);
}

// ---------------------------------------------------------------------------
// Transpose-pack x: fp32 [b][256][2304] -> bf16 FRAGMENT-MAJOR xT:
//   [b][nb=72][kc=16][lane=64][8]
//   value = x[b][c = kc*16 + (lane>>5)*8 + e][n = nb*32 + (lane&31)]
// ---------------------------------------------------------------------------
__global__ __launch_bounds__(256) void pack_xT(
    const float* __restrict__ x, short* __restrict__ xT)
{
    int n0 = blockIdx.x * 64, c0 = blockIdx.y * 64, b = blockIdx.z;
    __shared__ float sT[64][65];
    int tid = threadIdx.x, lane = tid & 63, wv = tid >> 6;
    for (int c = wv; c < 64; c += 4)
        sT[c][lane] = x[((size_t)b * CIN + c0 + c) * NTOK + n0 + lane];
    __syncthreads();
    int n = tid >> 2, c4 = (tid & 3) * 16;
    unsigned buf[8];
#pragma unroll
    for (int i = 0; i < 8; i++)
        buf[i] = f2bf(sT[c4 + 2 * i][n]) | (f2bf(sT[c4 + 2 * i + 1][n]) << 16);
    int n_tok = n0 + n;
    int l31n = n & 31;
    short* dst = xT + (((size_t)b * 72 + (n_tok >> 5)) * 16 + ((c0 + c4) >> 4)) * 512;
    ((uint4*)(dst + (0 * 32 + l31n) * 8))[0] = make_uint4(buf[0], buf[1], buf[2], buf[3]);
    ((uint4*)(dst + (1 * 32 + l31n) * 8))[0] = make_uint4(buf[4], buf[5], buf[6], buf[7]);
}

// ---------------------------------------------------------------------------
// QKV GEMM (MFMA): BM=128, BN=128, K=256, ALL operands fragment-major ->
// every load is a contiguous 1KB wave-load. rows o<1024 (q,k) -> fp32 qkf;
// rows >=1024 (v) -> bf16 vb FRAGMENT-MAJOR [b][hh][mb=72][j=4][lane=64][8].
// grid (18, 12, 2). 4 MFMA + 5 loads per k-chunk, unroll 2.
// ---------------------------------------------------------------------------
__global__ __launch_bounds__(256, 2) void gemm_qkv(
    const short* __restrict__ A,     // wqb frag-major
    const short* __restrict__ B,     // xT frag-major
    float* __restrict__ qkf, short* __restrict__ vb)
{
    int b = blockIdx.z;
    int o0 = blockIdx.y * 128;
    int n0 = blockIdx.x * 128;
    int tid = threadIdx.x, wv = tid >> 6, lane = tid & 63;
    int h = lane >> 5, l31 = lane & 31;

    const short* pa = A + ((size_t)(o0 >> 5) * 16) * 512 + lane * 8;
    const short* pb = B + (((size_t)b * 72 + (n0 >> 5) + wv) * 16) * 512 + lane * 8;

    f32x16 acc[4];
#pragma unroll
    for (int rb = 0; rb < 4; rb++)
#pragma unroll
        for (int r = 0; r < 16; r++) acc[rb][r] = 0.f;

#pragma unroll 2
    for (int kc = 0; kc < 16; kc++) {
        bfrag a0 = *(const bfrag*)(pa + (size_t)(0 * 16 + kc) * 512);
        bfrag a1 = *(const bfrag*)(pa + (size_t)(1 * 16 + kc) * 512);
        bfrag a2 = *(const bfrag*)(pa + (size_t)(2 * 16 + kc) * 512);
        bfrag a3 = *(const bfrag*)(pa + (size_t)(3 * 16 + kc) * 512);
        bfrag bb = *(const bfrag*)(pb + (size_t)kc * 512);
        acc[0] = __builtin_amdgcn_mfma_f32_32x32x16_bf16(a0, bb, acc[0], 0, 0, 0);
        acc[1] = __builtin_amdgcn_mfma_f32_32x32x16_bf16(a1, bb, acc[1], 0, 0, 0);
        acc[2] = __builtin_amdgcn_mfma_f32_32x32x16_bf16(a2, bb, acc[2], 0, 0, 0);
        acc[3] = __builtin_amdgcn_mfma_f32_32x32x16_bf16(a3, bb, acc[3], 0, 0, 0);
    }

    int nn = n0 + wv * 32 + l31;
    if (o0 < 1024) {
        float* Q = qkf + (size_t)b * 1024 * NTOK;
#pragma unroll
        for (int rb = 0; rb < 4; rb++)
#pragma unroll
            for (int r = 0; r < 16; r++) {
                int ml = (r & 3) + 8 * (r >> 2) + 4 * h;
                Q[(size_t)(o0 + rb * 32 + ml) * NTOK + nn] = acc[rb][r];
            }
    } else {
        // fragment-major V store
        short* V = vb + (size_t)b * 512 * NTOK;
        int ov = o0 - 1024;
        int mb = nn >> 5, jc = (nn >> 4) & 1, hv = (nn >> 3) & 1, e = nn & 7;
#pragma unroll
        for (int rb = 0; rb < 4; rb++)
#pragma unroll
            for (int r = 0; r < 16; r++) {
                int ml = (r & 3) + 8 * (r >> 2) + 4 * h;
                int row = ov + rb * 32 + ml;                 // 0..511
                int hh2 = row >> 6, dl = row & 63;
                int jr = dl >> 5, l31v = dl & 31;
                V[((((size_t)hh2 * 72 + mb) * 4 + jr * 2 + jc) * 64
                   + hv * 32 + l31v) * 8 + e] = (short)f2bf(acc[rb][r]);
            }
    }
}

// ---------------------------------------------------------------------------
// Row inverse L2-norm over tokens for q,k rows (2 x 1024 rows).
// ---------------------------------------------------------------------------
__global__ __launch_bounds__(256) void rownorm(
    const float* __restrict__ qkf, float* __restrict__ invn)
{
    int row = blockIdx.x;              // 0..2047
    int b = row >> 10, o = row & 1023;
    const float* p = qkf + ((size_t)b * 1024 + o) * NTOK;
    int tid = threadIdx.x;
    float s = 0.f;
    for (int n = tid; n < NTOK; n += 256) { float v = p[n]; s += v * v; }
#pragma unroll
    for (int off = 32; off > 0; off >>= 1) s += __shfl_down(s, off, 64);
    __shared__ float ws[4];
    if ((tid & 63) == 0) ws[tid >> 6] = s;
    __syncthreads();
    if (tid == 0) {
        float tot = ws[0] + ws[1] + ws[2] + ws[3];
        invn[row] = 1.f / fmaxf(sqrtf(tot), 1e-12f);
    }
}

// ---------------------------------------------------------------------------
// Pack normalized q,k -> bf16 FRAGMENT-MAJOR qkt:
//   [sel][bh][mb=72][i=4][lane=64][8]
//   value = QK[token mb*32 + (lane&31)][d = i*16 + (lane>>5)*8 + e]
// q additionally scaled by log2(e) so attention uses exp2 directly.
// ---------------------------------------------------------------------------
__global__ __launch_bounds__(256) void pack_qk(
    const float* __restrict__ qkf, const float* __restrict__ invn,
    short* __restrict__ qkt)
{
    int n0 = blockIdx.x * 64;
    int bh = blockIdx.y;
    int sel = blockIdx.z;
    int b = bh >> 3, h = bh & 7;
    const float* src = qkf + ((size_t)b * 1024 + sel * 512 + h * 64) * NTOK;
    int base = b * 1024 + sel * 512 + h * 64;
    float extra = sel == 0 ? LOG2E : 1.f;

    __shared__ float sT[64][65];
    int tid = threadIdx.x, lane = tid & 63, wv = tid >> 6;
    for (int d = wv; d < 64; d += 4)
        sT[d][lane] = src[(size_t)d * NTOK + n0 + lane] * (invn[base + d] * extra);
    __syncthreads();

    int n = tid >> 2, c4 = (tid & 3) * 16;
    unsigned buf[8];
#pragma unroll
    for (int i = 0; i < 8; i++)
        buf[i] = f2bf(sT[c4 + 2 * i][n]) | (f2bf(sT[c4 + 2 * i + 1][n]) << 16);
    int t = n0 + n;                       // token
    int mb = t >> 5, l31 = t & 31, fi = c4 >> 4;
    short* dst = qkt + (size_t)sel * ((size_t)16 * NTOK * 64)
               + (size_t)bh * NTOK * 64
               + ((size_t)mb * 4 + fi) * 512;
    // h-half 0: d = c4..c4+7 ; h-half 1: d = c4+8..c4+15
    ((uint4*)(dst + (0 * 32 + l31) * 8))[0] = make_uint4(buf[0], buf[1], buf[2], buf[3]);
    ((uint4*)(dst + (1 * 32 + l31) * 8))[0] = make_uint4(buf[4], buf[5], buf[6], buf[7]);
}

// ---------------------------------------------------------------------------
// Barrier-free attention, FAT waves + 4-way m-split.
// Each wave owns TWO 32-token n-groups (nb0, nb0+64) sharing one K/V load
// stream: 8 loads serve 16 MFMAs -> halves the L1/TA load traffic that
// bounds this kernel (663 -> 331 MB). 128-thread blocks keep the grid at
// 1152 (4.5 blocks/CU, tail 1.11x) with 2.25 waves/SIMD.
// Partials stored bf16 (4 splits fit in the dead qkf region).
// XCD locality: sharers of one (bh,ms) K/V-set differ by 64 (= 0 mod 8).
// Operands fragment-major: every load is a contiguous 1KB wave-load, with
// iter t+1's K/V register-prefetched during iter t's compute.
// ---------------------------------------------------------------------------
__global__ __launch_bounds__(128, 2) void attn_nb(
    const short* __restrict__ qkt,   // frag-major, q pre-scaled log2e
    const short* __restrict__ vb,    // frag-major
    short* __restrict__ Opart,       // [4 split][2][2304][512] bf16
    float* __restrict__ lsum)        // [4 split][16][2304] fp32
{
    int bid = blockIdx.x;
    int g = bid & 63;
    int bh = g >> 2, ms = g & 3;
    int ntile = bid >> 6;               // 0..17 (128 tokens each)
    int b = bh >> 3, hh = bh & 7;
    int tid = threadIdx.x, wv = tid >> 6, lane = tid & 63;
    int h = lane >> 5, l31 = lane & 31;
    int nb0 = ntile * 128 + wv * 32;
    int nb1 = nb0 + 64;
    int mb0 = ms * 18;                  // starting 32-token m-block

    const short* Qt = qkt + (size_t)bh * NTOK * 64;
    const short* kp = qkt + (size_t)16 * NTOK * 64 + (size_t)bh * NTOK * 64
                    + ((size_t)mb0 * 4) * 512 + lane * 8;
    const short* vp = vb + (((size_t)(b * 8 + hh) * 72 + mb0) * 4) * 512 + lane * 8;

    bfrag bQ0[4], bQ1[4];
    {
        const short* q0 = Qt + ((size_t)(nb0 >> 5) * 4) * 512 + lane * 8;
        const short* q1 = Qt + ((size_t)(nb1 >> 5) * 4) * 512 + lane * 8;
#pragma unroll
        for (int i = 0; i < 4; i++) {
            bQ0[i] = *(const bfrag*)(q0 + i * 512);
            bQ1[i] = *(const bfrag*)(q1 + i * 512);
        }
    }

    f32x16 aL0, aH0, aL1, aH1;
#pragma unroll
    for (int r = 0; r < 16; r++) { aL0[r] = 0.f; aH0[r] = 0.f; aL1[r] = 0.f; aH1[r] = 0.f; }
    float s00 = 0.f, s01 = 0.f, s10 = 0.f, s11 = 0.f;

    // prologue: load iter-0 frags
    bfrag ck[4], cv[4];
#pragma unroll
    for (int i = 0; i < 4; i++) {
        ck[i] = *(const bfrag*)(kp + i * 512);
        cv[i] = *(const bfrag*)(vp + i * 512);
    }

#pragma unroll 2
    for (int it = 0; it < 18; it++) {
        // prefetch iter t+1 (final iter reads one 4KB tile past the section;
        // that address is still inside the allocated workspace -> safe, unused)
        kp += 2048; vp += 2048;
        bfrag nk[4], nv[4];
#pragma unroll
        for (int i = 0; i < 4; i++) {
            nk[i] = *(const bfrag*)(kp + i * 512);
            nv[i] = *(const bfrag*)(vp + i * 512);
        }

        // ---- S^T for group 0, softmax, then group 1 (accS regs reused)
        bfrag P00, P01, P10, P11;
        {
            f32x16 accS;
#pragma unroll
            for (int r = 0; r < 16; r++) accS[r] = 0.f;
            accS = __builtin_amdgcn_mfma_f32_32x32x16_bf16(ck[0], bQ0[0], accS, 0, 0, 0);
            accS = __builtin_amdgcn_mfma_f32_32x32x16_bf16(ck[1], bQ0[1], accS, 0, 0, 0);
            accS = __builtin_amdgcn_mfma_f32_32x32x16_bf16(ck[2], bQ0[2], accS, 0, 0, 0);
            accS = __builtin_amdgcn_mfma_f32_32x32x16_bf16(ck[3], bQ0[3], accS, 0, 0, 0);
            softmax_frag(accS, h, s00, s01, P00, P01);
        }
        {
            f32x16 accS;
#pragma unroll
            for (int r = 0; r < 16; r++) accS[r] = 0.f;
            accS = __builtin_amdgcn_mfma_f32_32x32x16_bf16(ck[0], bQ1[0], accS, 0, 0, 0);
            accS = __builtin_amdgcn_mfma_f32_32x32x16_bf16(ck[1], bQ1[1], accS, 0, 0, 0);
            accS = __builtin_amdgcn_mfma_f32_32x32x16_bf16(ck[2], bQ1[2], accS, 0, 0, 0);
            accS = __builtin_amdgcn_mfma_f32_32x32x16_bf16(ck[3], bQ1[3], accS, 0, 0, 0);
            softmax_frag(accS, h, s10, s11, P10, P11);
        }
        // ---- O^T += P V (V frags shared across both n-groups)
        aL0 = __builtin_amdgcn_mfma_f32_32x32x16_bf16(P00, cv[0], aL0, 0, 0, 0);
        aL0 = __builtin_amdgcn_mfma_f32_32x32x16_bf16(P01, cv[1], aL0, 0, 0, 0);
        aH0 = __builtin_amdgcn_mfma_f32_32x32x16_bf16(P00, cv[2], aH0, 0, 0, 0);
        aH0 = __builtin_amdgcn_mfma_f32_32x32x16_bf16(P01, cv[3], aH0, 0, 0, 0);
        aL1 = __builtin_amdgcn_mfma_f32_32x32x16_bf16(P10, cv[0], aL1, 0, 0, 0);
        aL1 = __builtin_amdgcn_mfma_f32_32x32x16_bf16(P11, cv[1], aL1, 0, 0, 0);
        aH1 = __builtin_amdgcn_mfma_f32_32x32x16_bf16(P10, cv[2], aH1, 0, 0, 0);
        aH1 = __builtin_amdgcn_mfma_f32_32x32x16_bf16(P11, cv[3], aH1, 0, 0, 0);

        // rotate prefetched frags into current (renamed away by unroll)
#pragma unroll
        for (int i = 0; i < 4; i++) { ck[i] = nk[i]; cv[i] = nv[i]; }
    }

    // ---- row sums: fold partner half, direct store
    float p0 = s00 + s01;
    p0 += __shfl_xor(p0, 32, 64);
    float p1 = s10 + s11;
    p1 += __shfl_xor(p1, 32, 64);
    if (h == 0) {
        lsum[((size_t)ms * 16 + bh) * NTOK + nb0 + l31] = p0;
        lsum[((size_t)ms * 16 + bh) * NTOK + nb1 + l31] = p1;
    }

    // ---- O^T partial stores (bf16)
    short* Ob = Opart + (size_t)ms * (2ull * NTOK * HID)
              + (size_t)b * NTOK * HID + hh * 64;
#pragma unroll
    for (int r = 0; r < 16; r++) {
        int ml = (r & 3) + 8 * (r >> 2) + 4 * h;
        Ob[(size_t)(nb0 + ml) * HID + l31] = (short)f2bf(aL0[r]);
        Ob[(size_t)(nb0 + ml) * HID + 32 + l31] = (short)f2bf(aH0[r]);
        Ob[(size_t)(nb1 + ml) * HID + l31] = (short)f2bf(aL1[r]);
        Ob[(size_t)(nb1 + ml) * HID + 32 + l31] = (short)f2bf(aH1[r]);
    }
}

// ---------------------------------------------------------------------------
// Combine four m-splits (bf16 partials), normalize, pack bf16 aoT
// FRAGMENT-MAJOR [b][nb=72][kc=32][lane=64][8]. grid 1152 x 256.
// ---------------------------------------------------------------------------
__global__ __launch_bounds__(256) void combine(
    const short* __restrict__ Opart, const float* __restrict__ lsum,
    short* __restrict__ aoT)
{
    int s = blockIdx.x * 256 + threadIdx.x;       // slot
    int lane = s & 63, kc = (s >> 6) & 31, nbb = s >> 11;   // nbb 0..143
    int b = nbb >= 72 ? 1 : 0, nb = nbb - 72 * b;
    int h = lane >> 5, l31 = lane & 31;
    int n = nb * 32 + l31;
    int k0 = kc * 16 + h * 8;
    int hh = kc >> 2;                              // head = k/64
    float l = 0.f;
#pragma unroll
    for (int ms = 0; ms < 4; ms++)
        l += lsum[((size_t)ms * 16 + b * 8 + hh) * NTOK + n];
    float inv = 1.f / l;
    float a[8] = {0.f, 0.f, 0.f, 0.f, 0.f, 0.f, 0.f, 0.f};
#pragma unroll
    for (int ms = 0; ms < 4; ms++) {
        const short* P = Opart + (size_t)ms * (2ull * NTOK * HID)
                       + ((size_t)b * NTOK + n) * HID + k0;
        uint4 v = *(const uint4*)P;
        a[0] += __uint_as_float(v.x << 16);
        a[1] += __uint_as_float(v.x & 0xffff0000u);
        a[2] += __uint_as_float(v.y << 16);
        a[3] += __uint_as_float(v.y & 0xffff0000u);
        a[4] += __uint_as_float(v.z << 16);
        a[5] += __uint_as_float(v.z & 0xffff0000u);
        a[6] += __uint_as_float(v.w << 16);
        a[7] += __uint_as_float(v.w & 0xffff0000u);
    }
    unsigned b0 = f2bf(a[0] * inv) | (f2bf(a[1] * inv) << 16);
    unsigned b1 = f2bf(a[2] * inv) | (f2bf(a[3] * inv) << 16);
    unsigned b2 = f2bf(a[4] * inv) | (f2bf(a[5] * inv) << 16);
    unsigned b3 = f2bf(a[6] * inv) | (f2bf(a[7] * inv) << 16);
    *((uint4*)(aoT + (size_t)s * 8)) = make_uint4(b0, b1, b2, b3);
}

// ---------------------------------------------------------------------------
// Proj GEMM (MFMA, frag-major operands, direct store + bias). BM=64, BN=128,
// K=512. grid (18, 4, 2). 2 MFMA + 3 contiguous loads per k-chunk, unroll 4.
// ---------------------------------------------------------------------------
__global__ __launch_bounds__(256, 2) void gemm_proj(
    const short* __restrict__ A,     // wpb frag-major [ob=8][kc=32][64][8]
    const short* __restrict__ B,     // aoT frag-major [b][nb=72][kc=32][64][8]
    const float* __restrict__ bias, float* __restrict__ y)
{
    int b = blockIdx.z;
    int o0 = blockIdx.y * 64;
    int n0 = blockIdx.x * 128;
    int tid = threadIdx.x, wv = tid >> 6, lane = tid & 63;
    int h = lane >> 5, l31 = lane & 31;

    const short* pa = A + ((size_t)(o0 >> 5) * 32) * 512 + lane * 8;
    const short* pb = B + (((size_t)b * 72 + (n0 >> 5) + wv) * 32) * 512 + lane * 8;

    f32x16 acc0, acc1;
#pragma unroll
    for (int r = 0; r < 16; r++) { acc0[r] = 0.f; acc1[r] = 0.f; }

#pragma unroll 4
    for (int kc = 0; kc < 32; kc++) {
        bfrag a0 = *(const bfrag*)(pa + (size_t)kc * 512);
        bfrag a1 = *(const bfrag*)(pa + (size_t)(32 + kc) * 512);
        bfrag bb = *(const bfrag*)(pb + (size_t)kc * 512);
        acc0 = __builtin_amdgcn_mfma_f32_32x32x16_bf16(a0, bb, acc0, 0, 0, 0);
        acc1 = __builtin_amdgcn_mfma_f32_32x32x16_bf16(a1, bb, acc1, 0, 0, 0);
    }

    int nn = n0 + wv * 32 + l31;
#pragma unroll
    for (int r = 0; r < 16; r++) {
        int ml = (r & 3) + 8 * (r >> 2) + 4 * h;
        y[((size_t)b * CIN + o0 + ml) * NTOK + nn] = acc0[r] + bias[o0 + ml];
        y[((size_t)b * CIN + o0 + 32 + ml) * NTOK + nn] = acc1[r] + bias[o0 + 32 + ml];
    }
}

// ---------------------------------------------------------------------------
// Workspace (<= 36,446,208 B of 37,748,736):
//   [0, 18,874,368)           qkf fp32 [2][1024][2304]   (k3 -> k5)
//       then Opart bf16 [4 split][2][2304][512]          (k6 -> k7, exact fit)
//   [18,874,368, 23,592,960)  vb bf16 frag-major         (k3 -> k6)
//   [23,592,960, 33,030,144)  qkt bf16 frag-major        (k5 -> k6)
//       then aoT bf16 frag-major at 23,592,960           (k7 -> k8)
//   [33,030,144, 33,620,000~) lsum fp32 [4][16][2304]    (k6 -> k7, over dead xT)
//   [33,030,144, 35,389,440)  xT bf16 frag-major          (k2 -> k3, dead at k6)
//   [35,389,440, 36,175,872)  wqb bf16 frag-major
//   [36,175,872, 36,438,016)  wpb bf16 frag-major
//   [36,438,016, 36,446,208)  invn fp32 [2048]
// ---------------------------------------------------------------------------
extern "C" void kernel_launch(void* const* d_in, const int* in_sizes, int n_in,
                              void* d_out, int out_size, void* d_ws, size_t ws_size,
                              hipStream_t stream)
{
    const float* x      = (const float*)d_in[0];
    const float* w_qkv  = (const float*)d_in[1];
    const float* w_proj = (const float*)d_in[2];
    const float* b_proj = (const float*)d_in[3];
    float* y = (float*)d_out;

    float* qkf   = (float*)d_ws;
    short* Opart = (short*)d_ws;
    short* vb    = (short*)((char*)d_ws + 18874368);
    short* qkt   = (short*)((char*)d_ws + 23592960);
    short* aoT   = (short*)((char*)d_ws + 23592960);
    float* lsum  = (float*)((char*)d_ws + 33030144);
    short* xT    = (short*)((char*)d_ws + 33030144);
    short* wqb   = (short*)((char*)d_ws + 35389440);
    short* wpb   = (short*)((char*)d_ws + 36175872);
    float* invn  = (float*)((char*)d_ws + 36438016);

    // k1: pack both weights (frag-major)
    pack_weights<<<(1536 * 256 + 256 * 512) / 8 / 256, 256, 0, stream>>>(
        w_qkv, wqb, w_proj, wpb);
    // k2: transpose-pack x (frag-major)
    pack_xT<<<dim3(NTOK / 64, CIN / 64, BATCH), 256, 0, stream>>>(x, xT);
    // k3: QKV GEMM, all-contiguous operand loads (q,k fp32; v frag-major bf16)
    gemm_qkv<<<dim3(NTOK / 128, 1536 / 128, BATCH), 256, 0, stream>>>(
        wqb, xT, qkf, vb);
    // k4: inverse row norms
    rownorm<<<2048, 256, 0, stream>>>(qkf, invn);
    // k5: pack normalized q (x log2e), k -> fragment-major bf16
    pack_qk<<<dim3(NTOK / 64, BATCH * NH, 2), 256, 0, stream>>>(qkf, invn, qkt);
    // k6: attention — fat waves (2 n-groups), 1152 x 128-thread blocks
    attn_nb<<<1152, 128, 0, stream>>>(qkt, vb, Opart, lsum);
    // k7: combine 4 splits -> aoT frag-major bf16 (over dead qkt)
    combine<<<1152, 256, 0, stream>>>(Opart, lsum, aoT);
    // k8: proj GEMM, frag-major operands, direct store + bias
    gemm_proj<<<dim3(NTOK / 128, CIN / 64, BATCH), 256, 0, stream>>>(
        wpb, aoT, b_proj, y);
}

// Round 7
// 143.821 us; speedup vs baseline: 1.0022x; 1.0022x over previous
//
#include <hip/hip_runtime.h>
#include <math.h>

#define NTOK 2304      // 48*48 tokens
#define BATCH 2
#define CIN 256
#define HID 512        // 8 heads * 64
#define NH 8
#define LOG2E 1.44269504088896340736f

typedef __attribute__((ext_vector_type(8))) short bfrag;    // 8 bf16 (4 VGPRs)
typedef __attribute__((ext_vector_type(16))) float f32x16;  // MFMA 32x32 accumulator

#if __has_builtin(__builtin_amdgcn_exp2f)
#define EXP2(x) __builtin_amdgcn_exp2f(x)
#else
#define EXP2(x) exp2f(x)
#endif

// fp32 -> bf16 (RNE)
__device__ __forceinline__ unsigned f2bf(float f) {
    unsigned u = __float_as_uint(f);
    u += 0x7FFF + ((u >> 16) & 1);
    return u >> 16;
}

__device__ __forceinline__ float bf2f(unsigned short s) {
    return __uint_as_float(((unsigned)s) << 16);
}

// pack trunc(hi(b)) , trunc(hi(a)) -> one dword {bf16(b):bf16(a)} in 1 v_perm
__device__ __forceinline__ unsigned pk_trunc(float a, float b) {
    return __builtin_amdgcn_perm(__float_as_uint(b), __float_as_uint(a), 0x07060302u);
}

// exp2 + bf16-pack + lane^32 half-swap: accS (S^T quadrant, C-layout) ->
// two A-operand P frags; accumulates this lane's partial row sums (tree).
__device__ __forceinline__ void softmax_frag(
    const f32x16& accS, int h, float& ps0, float& ps1, bfrag& P0, bfrag& P1)
{
    unsigned dw[8];
    float e0[8], e1[8];
#pragma unroll
    for (int i = 0; i < 8; i++) {
        float plo = EXP2(accS[2 * i]);
        float phi = EXP2(accS[2 * i + 1]);
        dw[i] = pk_trunc(plo, phi);
        e0[i] = __uint_as_float(dw[i] << 16);
        e1[i] = __uint_as_float(dw[i] & 0xffff0000u);
    }
    ps0 += ((e0[0] + e0[1]) + (e0[2] + e0[3])) + ((e0[4] + e0[5]) + (e0[6] + e0[7]));
    ps1 += ((e1[0] + e1[1]) + (e1[2] + e1[3])) + ((e1[4] + e1[5]) + (e1[6] + e1[7]));
    unsigned sa0 = h ? dw[0] : dw[2], sb0 = h ? dw[1] : dw[3];
    unsigned sa1 = h ? dw[4] : dw[6], sb1 = h ? dw[5] : dw[7];
    unsigned ra0 = (unsigned)__shfl_xor((int)sa0, 32, 64);
    unsigned rb0 = (unsigned)__shfl_xor((int)sb0, 32, 64);
    unsigned ra1 = (unsigned)__shfl_xor((int)sa1, 32, 64);
    unsigned rb1 = (unsigned)__shfl_xor((int)sb1, 32, 64);
    union { bfrag f; unsigned u[4]; } U0, U1;
    U0.u[0] = h ? ra0 : dw[0];  U0.u[1] = h ? rb0 : dw[1];
    U0.u[2] = h ? dw[2] : ra0;  U0.u[3] = h ? dw[3] : rb0;
    U1.u[0] = h ? ra1 : dw[4];  U1.u[1] = h ? rb1 : dw[5];
    U1.u[2] = h ? dw[6] : ra1;  U1.u[3] = h ? dw[7] : rb1;
    P0 = U0.f; P1 = U1.f;
}

// ---------------------------------------------------------------------------
// Pack both weight matrices fp32 -> bf16 FRAGMENT-MAJOR in one dispatch.
// Block 0 additionally zeroes the sumsq accumulator (2048 fp32).
// ---------------------------------------------------------------------------
__global__ __launch_bounds__(256) void pack_weights(
    const float* __restrict__ wq, short* __restrict__ wqb,
    const float* __restrict__ wp, short* __restrict__ wpb,
    float* __restrict__ sumsq)
{
    if (blockIdx.x == 0) {
        ((float4*)sumsq)[threadIdx.x * 2] = make_float4(0.f, 0.f, 0.f, 0.f);
        ((float4*)sumsq)[threadIdx.x * 2 + 1] = make_float4(0.f, 0.f, 0.f, 0.f);
    }
    int e = (blockIdx.x * 256 + threadIdx.x) * 8;
    const int NQ = 1536 * 256;
    const float* src; short* dst;
    if (e < NQ) {
        int row = e >> 8, c = e & 255;
        int off = (((row >> 5) * 16 + (c >> 4)) * 64 + ((c >> 3) & 1) * 32 + (row & 31)) * 8;
        src = wq + e; dst = wqb + off;
    } else {
        int e2 = e - NQ;
        int row = e2 >> 9, c = e2 & 511;
        int off = (((row >> 5) * 32 + (c >> 4)) * 64 + ((c >> 3) & 1) * 32 + (row & 31)) * 8;
        src = wp + e2; dst = wpb + off;
    }
    float4 v0 = ((const float4*)src)[0];
    float4 v1 = ((const float4*)src)[1];
    unsigned b0 = f2bf(v0.x) | (f2bf(v0.y) << 16);
    unsigned b1 = f2bf(v0.z) | (f2bf(v0.w) << 16);
    unsigned b2 = f2bf(v1.x) | (f2bf(v1.y) << 16);
    unsigned b3 = f2bf(v1.z) | (f2bf(v1.w) << 16);
    *((uint4*)dst) = make_uint4(b0, b1, b2, b3);
}

// ---------------------------------------------------------------------------
// Transpose-pack x: fp32 [b][256][2304] -> bf16 FRAGMENT-MAJOR xT:
//   [b][nb=72][kc=16][lane=64][8]
// ---------------------------------------------------------------------------
__global__ __launch_bounds__(256) void pack_xT(
    const float* __restrict__ x, short* __restrict__ xT)
{
    int n0 = blockIdx.x * 64, c0 = blockIdx.y * 64, b = blockIdx.z;
    __shared__ float sT[64][65];
    int tid = threadIdx.x, lane = tid & 63, wv = tid >> 6;
    for (int c = wv; c < 64; c += 4)
        sT[c][lane] = x[((size_t)b * CIN + c0 + c) * NTOK + n0 + lane];
    __syncthreads();
    int n = tid >> 2, c4 = (tid & 3) * 16;
    unsigned buf[8];
#pragma unroll
    for (int i = 0; i < 8; i++)
        buf[i] = f2bf(sT[c4 + 2 * i][n]) | (f2bf(sT[c4 + 2 * i + 1][n]) << 16);
    int n_tok = n0 + n;
    int l31n = n & 31;
    short* dst = xT + (((size_t)b * 72 + (n_tok >> 5)) * 16 + ((c0 + c4) >> 4)) * 512;
    ((uint4*)(dst + (0 * 32 + l31n) * 8))[0] = make_uint4(buf[0], buf[1], buf[2], buf[3]);
    ((uint4*)(dst + (1 * 32 + l31n) * 8))[0] = make_uint4(buf[4], buf[5], buf[6], buf[7]);
}

// ---------------------------------------------------------------------------
// QKV GEMM (MFMA): BM=128, BN=128, K=256, all operands fragment-major.
// q,k rows (o<1024): store UNNORMALIZED bf16 directly into qkt frag-major
// layout [sel][bh][mb=72][i=4][lane=64][8]; NO in-kernel reduction (R4's
// shfl storm is the proven anti-pattern — sumsq is a separate tiny pass).
// v rows (>=1024): bf16 vb frag-major [b][hh][mb=72][j=4][lane=64][8].
// grid (18, 12, 2).
// ---------------------------------------------------------------------------
__global__ __launch_bounds__(256, 2) void gemm_qkv(
    const short* __restrict__ A,     // wqb frag-major
    const short* __restrict__ B,     // xT frag-major
    short* __restrict__ qku,         // qkt buffer (unnormalized at this stage)
    short* __restrict__ vb)
{
    int b = blockIdx.z;
    int o0 = blockIdx.y * 128;
    int n0 = blockIdx.x * 128;
    int tid = threadIdx.x, wv = tid >> 6, lane = tid & 63;
    int h = lane >> 5, l31 = lane & 31;

    const short* pa = A + ((size_t)(o0 >> 5) * 16) * 512 + lane * 8;
    const short* pb = B + (((size_t)b * 72 + (n0 >> 5) + wv) * 16) * 512 + lane * 8;

    f32x16 acc[4];
#pragma unroll
    for (int rb = 0; rb < 4; rb++)
#pragma unroll
        for (int r = 0; r < 16; r++) acc[rb][r] = 0.f;

#pragma unroll 2
    for (int kc = 0; kc < 16; kc++) {
        bfrag a0 = *(const bfrag*)(pa + (size_t)(0 * 16 + kc) * 512);
        bfrag a1 = *(const bfrag*)(pa + (size_t)(1 * 16 + kc) * 512);
        bfrag a2 = *(const bfrag*)(pa + (size_t)(2 * 16 + kc) * 512);
        bfrag a3 = *(const bfrag*)(pa + (size_t)(3 * 16 + kc) * 512);
        bfrag bb = *(const bfrag*)(pb + (size_t)kc * 512);
        acc[0] = __builtin_amdgcn_mfma_f32_32x32x16_bf16(a0, bb, acc[0], 0, 0, 0);
        acc[1] = __builtin_amdgcn_mfma_f32_32x32x16_bf16(a1, bb, acc[1], 0, 0, 0);
        acc[2] = __builtin_amdgcn_mfma_f32_32x32x16_bf16(a2, bb, acc[2], 0, 0, 0);
        acc[3] = __builtin_amdgcn_mfma_f32_32x32x16_bf16(a3, bb, acc[3], 0, 0, 0);
    }

    int nn = n0 + wv * 32 + l31;
    if (o0 < 1024) {
        int sel = o0 >> 9;                       // constant per block
        short* Qb = qku + (size_t)sel * (16 * NTOK * 64);
        int mbase = (nn >> 5) * 4, tl = nn & 31;
#pragma unroll
        for (int rb = 0; rb < 4; rb++)
#pragma unroll
            for (int r = 0; r < 16; r++) {
                int ml = (r & 3) + 8 * (r >> 2) + 4 * h;
                int o = o0 + rb * 32 + ml;       // 0..1023 (includes sel)
                int hh2 = (o >> 6) & 7, d = o & 63;
                Qb[(size_t)(b * 8 + hh2) * (NTOK * 64)
                   + (size_t)(mbase + (d >> 4)) * 512
                   + (((d >> 3) & 1) * 32 + tl) * 8 + (d & 7)] = (short)f2bf(acc[rb][r]);
            }
    } else {
        // fragment-major V store
        short* V = vb + (size_t)b * 512 * NTOK;
        int ov = o0 - 1024;
        int mb = nn >> 5, jc = (nn >> 4) & 1, hv = (nn >> 3) & 1, e = nn & 7;
#pragma unroll
        for (int rb = 0; rb < 4; rb++)
#pragma unroll
            for (int r = 0; r < 16; r++) {
                int ml = (r & 3) + 8 * (r >> 2) + 4 * h;
                int row = ov + rb * 32 + ml;                 // 0..511
                int hh2 = row >> 6, dl = row & 63;
                int jr = dl >> 5, l31v = dl & 31;
                V[((((size_t)hh2 * 72 + mb) * 4 + jr * 2 + jc) * 64
                   + hv * 32 + l31v) * 8 + e] = (short)f2bf(acc[rb][r]);
            }
    }
}

// ---------------------------------------------------------------------------
// Per-row sum of squares from bf16 qkt (streaming, frag-major friendly).
// grid 1152 x 64: bid = ((selbh*4 + i)*9 + mc); wave reads 8 mb-slots of 1KB,
// squares/accumulates 8 d-values per lane, 5-step butterfly over the 32
// token-lanes once at the end, 8 atomicAdds per half-wave.
// Norm from bf16 values: relative sumsq error ~2^-8/sqrt(2304) ~ 1e-4 (ok).
// ---------------------------------------------------------------------------
__global__ __launch_bounds__(64) void sumsq_qk(
    const short* __restrict__ qkt, float* __restrict__ sumsq)
{
    int bid = blockIdx.x;
    int mc = bid % 9;
    int rest = bid / 9;
    int i = rest & 3;
    int selbh = rest >> 2;                  // 0..31
    int lane = threadIdx.x;
    const short* p = qkt + (((size_t)selbh * 72 + mc * 8) * 4 + i) * 512 + lane * 8;
    float sq[8] = {0.f, 0.f, 0.f, 0.f, 0.f, 0.f, 0.f, 0.f};
#pragma unroll
    for (int m = 0; m < 8; m++) {
        bfrag v = *(const bfrag*)(p + (size_t)m * 2048);
#pragma unroll
        for (int e = 0; e < 8; e++) {
            float f = bf2f((unsigned short)v[e]);
            sq[e] += f * f;
        }
    }
#pragma unroll
    for (int off = 1; off <= 16; off <<= 1)
#pragma unroll
        for (int e = 0; e < 8; e++)
            sq[e] += __shfl_xor(sq[e], off, 64);
    if ((lane & 31) == 0) {
        int sel = selbh >> 4, bh = selbh & 15;
        int b = bh >> 3, hh = bh & 7, hsel = lane >> 5;
        int dbase = i * 16 + hsel * 8;
        float* dst = sumsq + b * 1024 + sel * 512 + hh * 64 + dbase;
#pragma unroll
        for (int e = 0; e < 8; e++) atomicAdd(dst + e, sq[e]);
    }
}

// ---------------------------------------------------------------------------
// In-place scale of qkt by per-row inverse L2 norm (q also x log2e).
// grid 2304 x 256. (Proven in R4.)
// ---------------------------------------------------------------------------
__global__ __launch_bounds__(256) void scale_qk(
    short* __restrict__ qkt, const float* __restrict__ sumsq)
{
    int s = blockIdx.x * 256 + threadIdx.x;       // frag slot, 0..589823
    int lane = s & 63;
    int rest = s >> 6;
    int fi = rest & 3;
    int selbh = rest / 288;                       // 0..31
    int sel = selbh >> 4, bh = selbh & 15;
    int b = bh >> 3, hh = bh & 7;
    int d0 = fi * 16 + (lane >> 5) * 8;
    const float* sp = sumsq + b * 1024 + sel * 512 + hh * 64 + d0;
    float scl = sel == 0 ? LOG2E : 1.f;
    float4 s0 = ((const float4*)sp)[0];
    float4 s1 = ((const float4*)sp)[1];
    float i0 = scl / fmaxf(sqrtf(s0.x), 1e-12f);
    float i1 = scl / fmaxf(sqrtf(s0.y), 1e-12f);
    float i2 = scl / fmaxf(sqrtf(s0.z), 1e-12f);
    float i3 = scl / fmaxf(sqrtf(s0.w), 1e-12f);
    float i4 = scl / fmaxf(sqrtf(s1.x), 1e-12f);
    float i5 = scl / fmaxf(sqrtf(s1.y), 1e-12f);
    float i6 = scl / fmaxf(sqrtf(s1.z), 1e-12f);
    float i7 = scl / fmaxf(sqrtf(s1.w), 1e-12f);
    uint4 v = ((uint4*)qkt)[s];
    unsigned o0w = f2bf(__uint_as_float(v.x << 16) * i0)
                 | (f2bf(__uint_as_float(v.x & 0xffff0000u) * i1) << 16);
    unsigned o1w = f2bf(__uint_as_float(v.y << 16) * i2)
                 | (f2bf(__uint_as_float(v.y & 0xffff0000u) * i3) << 16);
    unsigned o2w = f2bf(__uint_as_float(v.z << 16) * i4)
                 | (f2bf(__uint_as_float(v.z & 0xffff0000u) * i5) << 16);
    unsigned o3w = f2bf(__uint_as_float(v.w << 16) * i6)
                 | (f2bf(__uint_as_float(v.w & 0xffff0000u) * i7) << 16);
    ((uint4*)qkt)[s] = make_uint4(o0w, o1w, o2w, o3w);
}

// ---------------------------------------------------------------------------
// Barrier-free attention, fat waves + 4-way m-split (R6 structure).
// NEW: Opart partials stored FRAGMENT-MAJOR [ms][b][nb=72][kc=32][lane=64][8]
// so combine becomes a fully streaming kernel. Store math verified:
// slot value = O[b][n=nb*32+(wi&31)][k=kc*16+(wi>>5)*8+e].
// ---------------------------------------------------------------------------
__global__ __launch_bounds__(128, 2) void attn_nb(
    const short* __restrict__ qkt,   // frag-major, q pre-scaled log2e
    const short* __restrict__ vb,    // frag-major
    short* __restrict__ Opart,       // [4 split][2][72][32][64][8] bf16
    float* __restrict__ lsum)        // [4 split][16][2304] fp32
{
    int bid = blockIdx.x;
    int g = bid & 63;
    int bh = g >> 2, ms = g & 3;
    int ntile = bid >> 6;               // 0..17 (128 tokens each)
    int b = bh >> 3, hh = bh & 7;
    int tid = threadIdx.x, wv = tid >> 6, lane = tid & 63;
    int h = lane >> 5, l31 = lane & 31;
    int nb0 = ntile * 128 + wv * 32;
    int nb1 = nb0 + 64;
    int mb0 = ms * 18;                  // starting 32-token m-block

    const short* Qt = qkt + (size_t)bh * NTOK * 64;
    const short* kp = qkt + (size_t)16 * NTOK * 64 + (size_t)bh * NTOK * 64
                    + ((size_t)mb0 * 4) * 512 + lane * 8;
    const short* vp = vb + (((size_t)(b * 8 + hh) * 72 + mb0) * 4) * 512 + lane * 8;

    bfrag bQ0[4], bQ1[4];
    {
        const short* q0 = Qt + ((size_t)(nb0 >> 5) * 4) * 512 + lane * 8;
        const short* q1 = Qt + ((size_t)(nb1 >> 5) * 4) * 512 + lane * 8;
#pragma unroll
        for (int i = 0; i < 4; i++) {
            bQ0[i] = *(const bfrag*)(q0 + i * 512);
            bQ1[i] = *(const bfrag*)(q1 + i * 512);
        }
    }

    f32x16 aL0, aH0, aL1, aH1;
#pragma unroll
    for (int r = 0; r < 16; r++) { aL0[r] = 0.f; aH0[r] = 0.f; aL1[r] = 0.f; aH1[r] = 0.f; }
    float s00 = 0.f, s01 = 0.f, s10 = 0.f, s11 = 0.f;

    // prologue: load iter-0 frags
    bfrag ck[4], cv[4];
#pragma unroll
    for (int i = 0; i < 4; i++) {
        ck[i] = *(const bfrag*)(kp + i * 512);
        cv[i] = *(const bfrag*)(vp + i * 512);
    }

#pragma unroll 2
    for (int it = 0; it < 18; it++) {
        // prefetch iter t+1 (final iter reads one 4KB tile past the section;
        // that address is still inside the allocated workspace -> safe, unused)
        kp += 2048; vp += 2048;
        bfrag nk[4], nv[4];
#pragma unroll
        for (int i = 0; i < 4; i++) {
            nk[i] = *(const bfrag*)(kp + i * 512);
            nv[i] = *(const bfrag*)(vp + i * 512);
        }

        // ---- S^T for group 0, softmax, then group 1 (accS regs reused)
        bfrag P00, P01, P10, P11;
        {
            f32x16 accS;
#pragma unroll
            for (int r = 0; r < 16; r++) accS[r] = 0.f;
            accS = __builtin_amdgcn_mfma_f32_32x32x16_bf16(ck[0], bQ0[0], accS, 0, 0, 0);
            accS = __builtin_amdgcn_mfma_f32_32x32x16_bf16(ck[1], bQ0[1], accS, 0, 0, 0);
            accS = __builtin_amdgcn_mfma_f32_32x32x16_bf16(ck[2], bQ0[2], accS, 0, 0, 0);
            accS = __builtin_amdgcn_mfma_f32_32x32x16_bf16(ck[3], bQ0[3], accS, 0, 0, 0);
            softmax_frag(accS, h, s00, s01, P00, P01);
        }
        {
            f32x16 accS;
#pragma unroll
            for (int r = 0; r < 16; r++) accS[r] = 0.f;
            accS = __builtin_amdgcn_mfma_f32_32x32x16_bf16(ck[0], bQ1[0], accS, 0, 0, 0);
            accS = __builtin_amdgcn_mfma_f32_32x32x16_bf16(ck[1], bQ1[1], accS, 0, 0, 0);
            accS = __builtin_amdgcn_mfma_f32_32x32x16_bf16(ck[2], bQ1[2], accS, 0, 0, 0);
            accS = __builtin_amdgcn_mfma_f32_32x32x16_bf16(ck[3], bQ1[3], accS, 0, 0, 0);
            softmax_frag(accS, h, s10, s11, P10, P11);
        }
        // ---- O^T += P V (V frags shared across both n-groups)
        aL0 = __builtin_amdgcn_mfma_f32_32x32x16_bf16(P00, cv[0], aL0, 0, 0, 0);
        aL0 = __builtin_amdgcn_mfma_f32_32x32x16_bf16(P01, cv[1], aL0, 0, 0, 0);
        aH0 = __builtin_amdgcn_mfma_f32_32x32x16_bf16(P00, cv[2], aH0, 0, 0, 0);
        aH0 = __builtin_amdgcn_mfma_f32_32x32x16_bf16(P01, cv[3], aH0, 0, 0, 0);
        aL1 = __builtin_amdgcn_mfma_f32_32x32x16_bf16(P10, cv[0], aL1, 0, 0, 0);
        aL1 = __builtin_amdgcn_mfma_f32_32x32x16_bf16(P11, cv[1], aL1, 0, 0, 0);
        aH1 = __builtin_amdgcn_mfma_f32_32x32x16_bf16(P10, cv[2], aH1, 0, 0, 0);
        aH1 = __builtin_amdgcn_mfma_f32_32x32x16_bf16(P11, cv[3], aH1, 0, 0, 0);

        // rotate prefetched frags into current (renamed away by unroll)
#pragma unroll
        for (int i = 0; i < 4; i++) { ck[i] = nk[i]; cv[i] = nv[i]; }
    }

    // ---- row sums: fold partner half, direct store
    float p0 = s00 + s01;
    p0 += __shfl_xor(p0, 32, 64);
    float p1 = s10 + s11;
    p1 += __shfl_xor(p1, 32, 64);
    if (h == 0) {
        lsum[((size_t)ms * 16 + bh) * NTOK + nb0 + l31] = p0;
        lsum[((size_t)ms * 16 + bh) * NTOK + nb1 + l31] = p1;
    }

    // ---- O^T partial stores (bf16, FRAGMENT-MAJOR)
    short* Ob = Opart + ((size_t)ms * 2 + b) * (72 * 32 * 64 * 8);
    int nbs0 = nb0 >> 5, nbs1 = nb1 >> 5;
    int kcL = hh * 4 + (l31 >> 4);          // (k>>4) for aL (k = hh*64 + l31)
    int kcH = kcL + 2;                      // for aH (k = hh*64 + 32 + l31)
    int e = l31 & 7;
    int hs8 = ((l31 >> 3) & 1) * 32;
#pragma unroll
    for (int r = 0; r < 16; r++) {
        int ml = (r & 3) + 8 * (r >> 2) + 4 * h;
        int wi = hs8 + ml;                  // within-slot lane index
        Ob[(((size_t)nbs0 * 32 + kcL) * 64 + wi) * 8 + e] = (short)f2bf(aL0[r]);
        Ob[(((size_t)nbs0 * 32 + kcH) * 64 + wi) * 8 + e] = (short)f2bf(aH0[r]);
        Ob[(((size_t)nbs1 * 32 + kcL) * 64 + wi) * 8 + e] = (short)f2bf(aL1[r]);
        Ob[(((size_t)nbs1 * 32 + kcH) * 64 + wi) * 8 + e] = (short)f2bf(aH1[r]);
    }
}

// ---------------------------------------------------------------------------
// Combine four m-splits (bf16 frag-major partials), normalize, pack bf16 aoT
// FRAGMENT-MAJOR [b][nb=72][kc=32][lane=64][8]. Reads AND writes are in
// thread-index order -> fully streaming. grid 1152 x 256.
// ---------------------------------------------------------------------------
__global__ __launch_bounds__(256) void combine(
    const short* __restrict__ Opart, const float* __restrict__ lsum,
    short* __restrict__ aoT)
{
    int s = blockIdx.x * 256 + threadIdx.x;       // 0..294911
    int lane = s & 63, kc = (s >> 6) & 31, nbb = s >> 11;   // nbb = b*72+nb
    int b = nbb >= 72 ? 1 : 0, nb = nbb - 72 * b;
    int l31 = lane & 31;
    int n = nb * 32 + l31;
    int hh = kc >> 2;                              // head = k/64
    float l = 0.f;
#pragma unroll
    for (int ms = 0; ms < 4; ms++)
        l += lsum[((size_t)ms * 16 + b * 8 + hh) * NTOK + n];
    float inv = 1.f / l;
    const size_t MS = 2ull * 72 * 32 * 64 * 8;     // shorts per split
    float a[8] = {0.f, 0.f, 0.f, 0.f, 0.f, 0.f, 0.f, 0.f};
#pragma unroll
    for (int ms = 0; ms < 4; ms++) {
        uint4 v = *(const uint4*)(Opart + (size_t)ms * MS + (size_t)s * 8);
        a[0] += __uint_as_float(v.x << 16);
        a[1] += __uint_as_float(v.x & 0xffff0000u);
        a[2] += __uint_as_float(v.y << 16);
        a[3] += __uint_as_float(v.y & 0xffff0000u);
        a[4] += __uint_as_float(v.z << 16);
        a[5] += __uint_as_float(v.z & 0xffff0000u);
        a[6] += __uint_as_float(v.w << 16);
        a[7] += __uint_as_float(v.w & 0xffff0000u);
    }
    unsigned b0 = f2bf(a[0] * inv) | (f2bf(a[1] * inv) << 16);
    unsigned b1 = f2bf(a[2] * inv) | (f2bf(a[3] * inv) << 16);
    unsigned b2 = f2bf(a[4] * inv) | (f2bf(a[5] * inv) << 16);
    unsigned b3 = f2bf(a[6] * inv) | (f2bf(a[7] * inv) << 16);
    *((uint4*)(aoT + (size_t)s * 8)) = make_uint4(b0, b1, b2, b3);
}

// ---------------------------------------------------------------------------
// Proj GEMM (MFMA, frag-major operands, direct store + bias). BM=64, BN=128,
// K=512. grid (18, 4, 2).
// ---------------------------------------------------------------------------
__global__ __launch_bounds__(256, 2) void gemm_proj(
    const short* __restrict__ A,     // wpb frag-major [ob=8][kc=32][64][8]
    const short* __restrict__ B,     // aoT frag-major [b][nb=72][kc=32][64][8]
    const float* __restrict__ bias, float* __restrict__ y)
{
    int b = blockIdx.z;
    int o0 = blockIdx.y * 64;
    int n0 = blockIdx.x * 128;
    int tid = threadIdx.x, wv = tid >> 6, lane = tid & 63;
    int h = lane >> 5, l31 = lane & 31;

    const short* pa = A + ((size_t)(o0 >> 5) * 32) * 512 + lane * 8;
    const short* pb = B + (((size_t)b * 72 + (n0 >> 5) + wv) * 32) * 512 + lane * 8;

    f32x16 acc0, acc1;
#pragma unroll
    for (int r = 0; r < 16; r++) { acc0[r] = 0.f; acc1[r] = 0.f; }

#pragma unroll 4
    for (int kc = 0; kc < 32; kc++) {
        bfrag a0 = *(const bfrag*)(pa + (size_t)kc * 512);
        bfrag a1 = *(const bfrag*)(pa + (size_t)(32 + kc) * 512);
        bfrag bb = *(const bfrag*)(pb + (size_t)kc * 512);
        acc0 = __builtin_amdgcn_mfma_f32_32x32x16_bf16(a0, bb, acc0, 0, 0, 0);
        acc1 = __builtin_amdgcn_mfma_f32_32x32x16_bf16(a1, bb, acc1, 0, 0, 0);
    }

    int nn = n0 + wv * 32 + l31;
#pragma unroll
    for (int r = 0; r < 16; r++) {
        int ml = (r & 3) + 8 * (r >> 2) + 4 * h;
        y[((size_t)b * CIN + o0 + ml) * NTOK + nn] = acc0[r] + bias[o0 + ml];
        y[((size_t)b * CIN + o0 + 32 + ml) * NTOK + nn] = acc1[r] + bias[o0 + 32 + ml];
    }
}

// ---------------------------------------------------------------------------
// Workspace (<= 36,446,208 B of 37,748,736):
//   [0, 18,874,368)           Opart bf16 frag-major [4][2][72][32][64][8]
//                                                          (k6 -> k7)
//   [18,874,368, 23,592,960)  vb bf16 frag-major         (k3 -> k6)
//   [23,592,960, 33,030,144)  qkt bf16 frag-major        (k3 -> k6; scaled
//                              in place k4/k5); aoT overlays (k7 -> k8)
//   [33,030,144, 33,620,000~) lsum fp32 [4][16][2304]    (k6 -> k7, over dead xT)
//   [33,030,144, 35,389,440)  xT bf16 frag-major          (k2 -> k3, dead at k6)
//   [35,389,440, 36,175,872)  wqb bf16 frag-major
//   [36,175,872, 36,438,016)  wpb bf16 frag-major
//   [36,438,016, 36,446,208)  sumsq fp32 [2048]          (k1 zero, k4 acc, k5 read)
// ---------------------------------------------------------------------------
extern "C" void kernel_launch(void* const* d_in, const int* in_sizes, int n_in,
                              void* d_out, int out_size, void* d_ws, size_t ws_size,
                              hipStream_t stream)
{
    const float* x      = (const float*)d_in[0];
    const float* w_qkv  = (const float*)d_in[1];
    const float* w_proj = (const float*)d_in[2];
    const float* b_proj = (const float*)d_in[3];
    float* y = (float*)d_out;

    short* Opart = (short*)d_ws;
    short* vb    = (short*)((char*)d_ws + 18874368);
    short* qkt   = (short*)((char*)d_ws + 23592960);
    short* aoT   = (short*)((char*)d_ws + 23592960);
    float* lsum  = (float*)((char*)d_ws + 33030144);
    short* xT    = (short*)((char*)d_ws + 33030144);
    short* wqb   = (short*)((char*)d_ws + 35389440);
    short* wpb   = (short*)((char*)d_ws + 36175872);
    float* sumsq = (float*)((char*)d_ws + 36438016);

    // k1: pack both weights (frag-major) + zero sumsq
    pack_weights<<<(1536 * 256 + 256 * 512) / 8 / 256, 256, 0, stream>>>(
        w_qkv, wqb, w_proj, wpb, sumsq);
    // k2: transpose-pack x (frag-major)
    pack_xT<<<dim3(NTOK / 64, CIN / 64, BATCH), 256, 0, stream>>>(x, xT);
    // k3: QKV GEMM -> unnormalized q,k bf16 frag-major; v frag-major
    gemm_qkv<<<dim3(NTOK / 128, 1536 / 128, BATCH), 256, 0, stream>>>(
        wqb, xT, qkt, vb);
    // k4: per-row sum of squares from bf16 qkt (streaming + atomics)
    sumsq_qk<<<1152, 64, 0, stream>>>(qkt, sumsq);
    // k5: in-place normalize q (x log2e), k
    scale_qk<<<2304, 256, 0, stream>>>(qkt, sumsq);
    // k6: attention — fat waves (2 n-groups), 4-way m-split, frag-major Opart
    attn_nb<<<1152, 128, 0, stream>>>(qkt, vb, Opart, lsum);
    // k7: combine 4 splits (streaming) -> aoT frag-major bf16 (over dead qkt)
    combine<<<1152, 256, 0, stream>>>(Opart, lsum, aoT);
    // k8: proj GEMM, frag-major operands, direct store + bias
    gemm_proj<<<dim3(NTOK / 128, CIN / 64, BATCH), 256, 0, stream>>>(
        wpb, aoT, b_proj, y);
}

// Round 8
// 143.789 us; speedup vs baseline: 1.0024x; 1.0002x over previous
//
#include <hip/hip_runtime.h>
#include <math.h>

#define NTOK 2304      // 48*48 tokens
#define BATCH 2
#define CIN 256
#define HID 512        // 8 heads * 64
#define NH 8
#define LOG2E 1.44269504088896340736f

typedef __attribute__((ext_vector_type(8))) short bfrag;    // 8 bf16 (4 VGPRs)
typedef __attribute__((ext_vector_type(16))) float f32x16;  // MFMA 32x32 accumulator

#if __has_builtin(__builtin_amdgcn_exp2f)
#define EXP2(x) __builtin_amdgcn_exp2f(x)
#else
#define EXP2(x) exp2f(x)
#endif

// fp32 -> bf16 (RNE)
__device__ __forceinline__ unsigned f2bf(float f) {
    unsigned u = __float_as_uint(f);
    u += 0x7FFF + ((u >> 16) & 1);
    return u >> 16;
}

__device__ __forceinline__ float bf2f(unsigned short s) {
    return __uint_as_float(((unsigned)s) << 16);
}

// pack trunc(hi(b)) , trunc(hi(a)) -> one dword {bf16(b):bf16(a)} in 1 v_perm
__device__ __forceinline__ unsigned pk_trunc(float a, float b) {
    return __builtin_amdgcn_perm(__float_as_uint(b), __float_as_uint(a), 0x07060302u);
}

// exp2 + bf16-pack + lane^32 half-swap: accS (S^T quadrant, C-layout) ->
// two A-operand P frags; accumulates this lane's partial row sums (tree).
__device__ __forceinline__ void softmax_frag(
    const f32x16& accS, int h, float& ps0, float& ps1, bfrag& P0, bfrag& P1)
{
    unsigned dw[8];
    float e0[8], e1[8];
#pragma unroll
    for (int i = 0; i < 8; i++) {
        float plo = EXP2(accS[2 * i]);
        float phi = EXP2(accS[2 * i + 1]);
        dw[i] = pk_trunc(plo, phi);
        e0[i] = __uint_as_float(dw[i] << 16);
        e1[i] = __uint_as_float(dw[i] & 0xffff0000u);
    }
    ps0 += ((e0[0] + e0[1]) + (e0[2] + e0[3])) + ((e0[4] + e0[5]) + (e0[6] + e0[7]));
    ps1 += ((e1[0] + e1[1]) + (e1[2] + e1[3])) + ((e1[4] + e1[5]) + (e1[6] + e1[7]));
    unsigned sa0 = h ? dw[0] : dw[2], sb0 = h ? dw[1] : dw[3];
    unsigned sa1 = h ? dw[4] : dw[6], sb1 = h ? dw[5] : dw[7];
    unsigned ra0 = (unsigned)__shfl_xor((int)sa0, 32, 64);
    unsigned rb0 = (unsigned)__shfl_xor((int)sb0, 32, 64);
    unsigned ra1 = (unsigned)__shfl_xor((int)sa1, 32, 64);
    unsigned rb1 = (unsigned)__shfl_xor((int)sb1, 32, 64);
    union { bfrag f; unsigned u[4]; } U0, U1;
    U0.u[0] = h ? ra0 : dw[0];  U0.u[1] = h ? rb0 : dw[1];
    U0.u[2] = h ? dw[2] : ra0;  U0.u[3] = h ? dw[3] : rb0;
    U1.u[0] = h ? ra1 : dw[4];  U1.u[1] = h ? rb1 : dw[5];
    U1.u[2] = h ? dw[6] : ra1;  U1.u[3] = h ? dw[7] : rb1;
    P0 = U0.f; P1 = U1.f;
}

// ---------------------------------------------------------------------------
// Merged input pack: one dispatch does BOTH weight packing (frag-major) and
// x transpose-pack (frag-major). Block-uniform branch; saves one launch.
//   bid <  288 : pack_xT tile (n0, c0, b)
//   bid >= 288 : pack_weights chunk (bid 288 also zeroes sumsq)
// ---------------------------------------------------------------------------
__global__ __launch_bounds__(256) void pack_all(
    const float* __restrict__ wq, short* __restrict__ wqb,
    const float* __restrict__ wp, short* __restrict__ wpb,
    const float* __restrict__ x, short* __restrict__ xT,
    float* __restrict__ sumsq)
{
    int bid = blockIdx.x;
    if (bid < 288) {
        int n0 = (bid % 36) * 64, c0 = ((bid / 36) & 3) * 64, b = bid / 144;
        __shared__ float sT[64][65];
        int tid = threadIdx.x, lane = tid & 63, wv = tid >> 6;
        for (int c = wv; c < 64; c += 4)
            sT[c][lane] = x[((size_t)b * CIN + c0 + c) * NTOK + n0 + lane];
        __syncthreads();
        int n = tid >> 2, c4 = (tid & 3) * 16;
        unsigned buf[8];
#pragma unroll
        for (int i = 0; i < 8; i++)
            buf[i] = f2bf(sT[c4 + 2 * i][n]) | (f2bf(sT[c4 + 2 * i + 1][n]) << 16);
        int n_tok = n0 + n;
        int l31n = n & 31;
        short* dst = xT + (((size_t)b * 72 + (n_tok >> 5)) * 16 + ((c0 + c4) >> 4)) * 512;
        ((uint4*)(dst + (0 * 32 + l31n) * 8))[0] = make_uint4(buf[0], buf[1], buf[2], buf[3]);
        ((uint4*)(dst + (1 * 32 + l31n) * 8))[0] = make_uint4(buf[4], buf[5], buf[6], buf[7]);
    } else {
        if (bid == 288) {
            ((float4*)sumsq)[threadIdx.x * 2] = make_float4(0.f, 0.f, 0.f, 0.f);
            ((float4*)sumsq)[threadIdx.x * 2 + 1] = make_float4(0.f, 0.f, 0.f, 0.f);
        }
        int e = ((bid - 288) * 256 + threadIdx.x) * 8;
        const int NQ = 1536 * 256;
        const float* src; short* dst;
        if (e < NQ) {
            int row = e >> 8, c = e & 255;
            int off = (((row >> 5) * 16 + (c >> 4)) * 64 + ((c >> 3) & 1) * 32 + (row & 31)) * 8;
            src = wq + e; dst = wqb + off;
        } else {
            int e2 = e - NQ;
            int row = e2 >> 9, c = e2 & 511;
            int off = (((row >> 5) * 32 + (c >> 4)) * 64 + ((c >> 3) & 1) * 32 + (row & 31)) * 8;
            src = wp + e2; dst = wpb + off;
        }
        float4 v0 = ((const float4*)src)[0];
        float4 v1 = ((const float4*)src)[1];
        unsigned b0 = f2bf(v0.x) | (f2bf(v0.y) << 16);
        unsigned b1 = f2bf(v0.z) | (f2bf(v0.w) << 16);
        unsigned b2 = f2bf(v1.x) | (f2bf(v1.y) << 16);
        unsigned b3 = f2bf(v1.z) | (f2bf(v1.w) << 16);
        *((uint4*)dst) = make_uint4(b0, b1, b2, b3);
    }
}

// ---------------------------------------------------------------------------
// QKV GEMM (MFMA): BM=128, BN=128, K=256, all operands fragment-major.
// q,k rows (o<1024): store UNNORMALIZED bf16 directly into qkt frag-major
// layout via COALESCED uint2 stores: the C-layout's runs of 4 consecutive
// o-values (ml=(r&3)+8(r>>2)+4h) land at consecutive e=4h+j in one 16B slot,
// so each (rb,q) pair is one 8B store and the wave tiles a 512B segment.
// (Replaces R7's 64 scattered 2B stores/thread — that was the regression.)
// v rows (>=1024): bf16 vb frag-major [b][hh][mb=72][j=4][lane=64][8].
// grid (18, 12, 2).
// ---------------------------------------------------------------------------
__global__ __launch_bounds__(256, 2) void gemm_qkv(
    const short* __restrict__ A,     // wqb frag-major
    const short* __restrict__ B,     // xT frag-major
    short* __restrict__ qku,         // qkt buffer (unnormalized at this stage)
    short* __restrict__ vb)
{
    int b = blockIdx.z;
    int o0 = blockIdx.y * 128;
    int n0 = blockIdx.x * 128;
    int tid = threadIdx.x, wv = tid >> 6, lane = tid & 63;
    int h = lane >> 5, l31 = lane & 31;

    const short* pa = A + ((size_t)(o0 >> 5) * 16) * 512 + lane * 8;
    const short* pb = B + (((size_t)b * 72 + (n0 >> 5) + wv) * 16) * 512 + lane * 8;

    f32x16 acc[4];
#pragma unroll
    for (int rb = 0; rb < 4; rb++)
#pragma unroll
        for (int r = 0; r < 16; r++) acc[rb][r] = 0.f;

#pragma unroll 2
    for (int kc = 0; kc < 16; kc++) {
        bfrag a0 = *(const bfrag*)(pa + (size_t)(0 * 16 + kc) * 512);
        bfrag a1 = *(const bfrag*)(pa + (size_t)(1 * 16 + kc) * 512);
        bfrag a2 = *(const bfrag*)(pa + (size_t)(2 * 16 + kc) * 512);
        bfrag a3 = *(const bfrag*)(pa + (size_t)(3 * 16 + kc) * 512);
        bfrag bb = *(const bfrag*)(pb + (size_t)kc * 512);
        acc[0] = __builtin_amdgcn_mfma_f32_32x32x16_bf16(a0, bb, acc[0], 0, 0, 0);
        acc[1] = __builtin_amdgcn_mfma_f32_32x32x16_bf16(a1, bb, acc[1], 0, 0, 0);
        acc[2] = __builtin_amdgcn_mfma_f32_32x32x16_bf16(a2, bb, acc[2], 0, 0, 0);
        acc[3] = __builtin_amdgcn_mfma_f32_32x32x16_bf16(a3, bb, acc[3], 0, 0, 0);
    }

    int nn = n0 + wv * 32 + l31;
    if (o0 < 1024) {
        int sel = o0 >> 9;                       // constant per block
        short* Qb = qku + (size_t)sel * (16 * NTOK * 64);
        int oo = o0 & 511;                       // row base within sel
        int tl = nn & 31;
        size_t base_mb = (size_t)(nn >> 5) * 4;  // mb*4
#pragma unroll
        for (int rb = 0; rb < 4; rb++) {
            int hh2 = (oo + rb * 32) >> 6;
            int ihi = (rb & 1) * 2;
            short* Qbb = Qb + (size_t)(b * 8 + hh2) * (NTOK * 64);
#pragma unroll
            for (int q = 0; q < 4; q++) {
                int i = ihi + (q >> 1);
                unsigned lo = f2bf(acc[rb][4 * q])     | (f2bf(acc[rb][4 * q + 1]) << 16);
                unsigned hi = f2bf(acc[rb][4 * q + 2]) | (f2bf(acc[rb][4 * q + 3]) << 16);
                *(uint2*)(Qbb + (base_mb + i) * 512 + ((q & 1) * 32 + tl) * 8 + 4 * h)
                    = make_uint2(lo, hi);
            }
        }
    } else {
        // fragment-major V store
        short* V = vb + (size_t)b * 512 * NTOK;
        int ov = o0 - 1024;
        int mb = nn >> 5, jc = (nn >> 4) & 1, hv = (nn >> 3) & 1, e = nn & 7;
#pragma unroll
        for (int rb = 0; rb < 4; rb++)
#pragma unroll
            for (int r = 0; r < 16; r++) {
                int ml = (r & 3) + 8 * (r >> 2) + 4 * h;
                int row = ov + rb * 32 + ml;                 // 0..511
                int hh2 = row >> 6, dl = row & 63;
                int jr = dl >> 5, l31v = dl & 31;
                V[((((size_t)hh2 * 72 + mb) * 4 + jr * 2 + jc) * 64
                   + hv * 32 + l31v) * 8 + e] = (short)f2bf(acc[rb][r]);
            }
    }
}

// ---------------------------------------------------------------------------
// Per-row sum of squares from bf16 qkt (streaming, frag-major friendly).
// grid 1152 x 64. Norm-from-bf16 relative error ~1e-4 (verified R7: absmax
// unchanged).
// ---------------------------------------------------------------------------
__global__ __launch_bounds__(64) void sumsq_qk(
    const short* __restrict__ qkt, float* __restrict__ sumsq)
{
    int bid = blockIdx.x;
    int mc = bid % 9;
    int rest = bid / 9;
    int i = rest & 3;
    int selbh = rest >> 2;                  // 0..31
    int lane = threadIdx.x;
    const short* p = qkt + (((size_t)selbh * 72 + mc * 8) * 4 + i) * 512 + lane * 8;
    float sq[8] = {0.f, 0.f, 0.f, 0.f, 0.f, 0.f, 0.f, 0.f};
#pragma unroll
    for (int m = 0; m < 8; m++) {
        bfrag v = *(const bfrag*)(p + (size_t)m * 2048);
#pragma unroll
        for (int e = 0; e < 8; e++) {
            float f = bf2f((unsigned short)v[e]);
            sq[e] += f * f;
        }
    }
#pragma unroll
    for (int off = 1; off <= 16; off <<= 1)
#pragma unroll
        for (int e = 0; e < 8; e++)
            sq[e] += __shfl_xor(sq[e], off, 64);
    if ((lane & 31) == 0) {
        int sel = selbh >> 4, bh = selbh & 15;
        int b = bh >> 3, hh = bh & 7, hsel = lane >> 5;
        int dbase = i * 16 + hsel * 8;
        float* dst = sumsq + b * 1024 + sel * 512 + hh * 64 + dbase;
#pragma unroll
        for (int e = 0; e < 8; e++) atomicAdd(dst + e, sq[e]);
    }
}

// ---------------------------------------------------------------------------
// In-place scale of qkt by per-row inverse L2 norm (q also x log2e).
// grid 2304 x 256. (Proven R4/R7.)
// ---------------------------------------------------------------------------
__global__ __launch_bounds__(256) void scale_qk(
    short* __restrict__ qkt, const float* __restrict__ sumsq)
{
    int s = blockIdx.x * 256 + threadIdx.x;       // frag slot, 0..589823
    int lane = s & 63;
    int rest = s >> 6;
    int fi = rest & 3;
    int selbh = rest / 288;                       // 0..31
    int sel = selbh >> 4, bh = selbh & 15;
    int b = bh >> 3, hh = bh & 7;
    int d0 = fi * 16 + (lane >> 5) * 8;
    const float* sp = sumsq + b * 1024 + sel * 512 + hh * 64 + d0;
    float scl = sel == 0 ? LOG2E : 1.f;
    float4 s0 = ((const float4*)sp)[0];
    float4 s1 = ((const float4*)sp)[1];
    float i0 = scl / fmaxf(sqrtf(s0.x), 1e-12f);
    float i1 = scl / fmaxf(sqrtf(s0.y), 1e-12f);
    float i2 = scl / fmaxf(sqrtf(s0.z), 1e-12f);
    float i3 = scl / fmaxf(sqrtf(s0.w), 1e-12f);
    float i4 = scl / fmaxf(sqrtf(s1.x), 1e-12f);
    float i5 = scl / fmaxf(sqrtf(s1.y), 1e-12f);
    float i6 = scl / fmaxf(sqrtf(s1.z), 1e-12f);
    float i7 = scl / fmaxf(sqrtf(s1.w), 1e-12f);
    uint4 v = ((uint4*)qkt)[s];
    unsigned o0w = f2bf(__uint_as_float(v.x << 16) * i0)
                 | (f2bf(__uint_as_float(v.x & 0xffff0000u) * i1) << 16);
    unsigned o1w = f2bf(__uint_as_float(v.y << 16) * i2)
                 | (f2bf(__uint_as_float(v.y & 0xffff0000u) * i3) << 16);
    unsigned o2w = f2bf(__uint_as_float(v.z << 16) * i4)
                 | (f2bf(__uint_as_float(v.z & 0xffff0000u) * i5) << 16);
    unsigned o3w = f2bf(__uint_as_float(v.w << 16) * i6)
                 | (f2bf(__uint_as_float(v.w & 0xffff0000u) * i7) << 16);
    ((uint4*)qkt)[s] = make_uint4(o0w, o1w, o2w, o3w);
}

// ---------------------------------------------------------------------------
// Barrier-free attention, fat waves + 4-way m-split, frag-major Opart
// (unchanged from R7 — passed, absmax unchanged).
// ---------------------------------------------------------------------------
__global__ __launch_bounds__(128, 2) void attn_nb(
    const short* __restrict__ qkt,   // frag-major, q pre-scaled log2e
    const short* __restrict__ vb,    // frag-major
    short* __restrict__ Opart,       // [4 split][2][72][32][64][8] bf16
    float* __restrict__ lsum)        // [4 split][16][2304] fp32
{
    int bid = blockIdx.x;
    int g = bid & 63;
    int bh = g >> 2, ms = g & 3;
    int ntile = bid >> 6;               // 0..17 (128 tokens each)
    int b = bh >> 3, hh = bh & 7;
    int tid = threadIdx.x, wv = tid >> 6, lane = tid & 63;
    int h = lane >> 5, l31 = lane & 31;
    int nb0 = ntile * 128 + wv * 32;
    int nb1 = nb0 + 64;
    int mb0 = ms * 18;                  // starting 32-token m-block

    const short* Qt = qkt + (size_t)bh * NTOK * 64;
    const short* kp = qkt + (size_t)16 * NTOK * 64 + (size_t)bh * NTOK * 64
                    + ((size_t)mb0 * 4) * 512 + lane * 8;
    const short* vp = vb + (((size_t)(b * 8 + hh) * 72 + mb0) * 4) * 512 + lane * 8;

    bfrag bQ0[4], bQ1[4];
    {
        const short* q0 = Qt + ((size_t)(nb0 >> 5) * 4) * 512 + lane * 8;
        const short* q1 = Qt + ((size_t)(nb1 >> 5) * 4) * 512 + lane * 8;
#pragma unroll
        for (int i = 0; i < 4; i++) {
            bQ0[i] = *(const bfrag*)(q0 + i * 512);
            bQ1[i] = *(const bfrag*)(q1 + i * 512);
        }
    }

    f32x16 aL0, aH0, aL1, aH1;
#pragma unroll
    for (int r = 0; r < 16; r++) { aL0[r] = 0.f; aH0[r] = 0.f; aL1[r] = 0.f; aH1[r] = 0.f; }
    float s00 = 0.f, s01 = 0.f, s10 = 0.f, s11 = 0.f;

    // prologue: load iter-0 frags
    bfrag ck[4], cv[4];
#pragma unroll
    for (int i = 0; i < 4; i++) {
        ck[i] = *(const bfrag*)(kp + i * 512);
        cv[i] = *(const bfrag*)(vp + i * 512);
    }

#pragma unroll 2
    for (int it = 0; it < 18; it++) {
        // prefetch iter t+1 (final iter reads one 4KB tile past the section;
        // that address is still inside the allocated workspace -> safe, unused)
        kp += 2048; vp += 2048;
        bfrag nk[4], nv[4];
#pragma unroll
        for (int i = 0; i < 4; i++) {
            nk[i] = *(const bfrag*)(kp + i * 512);
            nv[i] = *(const bfrag*)(vp + i * 512);
        }

        // ---- S^T for group 0, softmax, then group 1 (accS regs reused)
        bfrag P00, P01, P10, P11;
        {
            f32x16 accS;
#pragma unroll
            for (int r = 0; r < 16; r++) accS[r] = 0.f;
            accS = __builtin_amdgcn_mfma_f32_32x32x16_bf16(ck[0], bQ0[0], accS, 0, 0, 0);
            accS = __builtin_amdgcn_mfma_f32_32x32x16_bf16(ck[1], bQ0[1], accS, 0, 0, 0);
            accS = __builtin_amdgcn_mfma_f32_32x32x16_bf16(ck[2], bQ0[2], accS, 0, 0, 0);
            accS = __builtin_amdgcn_mfma_f32_32x32x16_bf16(ck[3], bQ0[3], accS, 0, 0, 0);
            softmax_frag(accS, h, s00, s01, P00, P01);
        }
        {
            f32x16 accS;
#pragma unroll
            for (int r = 0; r < 16; r++) accS[r] = 0.f;
            accS = __builtin_amdgcn_mfma_f32_32x32x16_bf16(ck[0], bQ1[0], accS, 0, 0, 0);
            accS = __builtin_amdgcn_mfma_f32_32x32x16_bf16(ck[1], bQ1[1], accS, 0, 0, 0);
            accS = __builtin_amdgcn_mfma_f32_32x32x16_bf16(ck[2], bQ1[2], accS, 0, 0, 0);
            accS = __builtin_amdgcn_mfma_f32_32x32x16_bf16(ck[3], bQ1[3], accS, 0, 0, 0);
            softmax_frag(accS, h, s10, s11, P10, P11);
        }
        // ---- O^T += P V (V frags shared across both n-groups)
        aL0 = __builtin_amdgcn_mfma_f32_32x32x16_bf16(P00, cv[0], aL0, 0, 0, 0);
        aL0 = __builtin_amdgcn_mfma_f32_32x32x16_bf16(P01, cv[1], aL0, 0, 0, 0);
        aH0 = __builtin_amdgcn_mfma_f32_32x32x16_bf16(P00, cv[2], aH0, 0, 0, 0);
        aH0 = __builtin_amdgcn_mfma_f32_32x32x16_bf16(P01, cv[3], aH0, 0, 0, 0);
        aL1 = __builtin_amdgcn_mfma_f32_32x32x16_bf16(P10, cv[0], aL1, 0, 0, 0);
        aL1 = __builtin_amdgcn_mfma_f32_32x32x16_bf16(P11, cv[1], aL1, 0, 0, 0);
        aH1 = __builtin_amdgcn_mfma_f32_32x32x16_bf16(P10, cv[2], aH1, 0, 0, 0);
        aH1 = __builtin_amdgcn_mfma_f32_32x32x16_bf16(P11, cv[3], aH1, 0, 0, 0);

        // rotate prefetched frags into current (renamed away by unroll)
#pragma unroll
        for (int i = 0; i < 4; i++) { ck[i] = nk[i]; cv[i] = nv[i]; }
    }

    // ---- row sums: fold partner half, direct store
    float p0 = s00 + s01;
    p0 += __shfl_xor(p0, 32, 64);
    float p1 = s10 + s11;
    p1 += __shfl_xor(p1, 32, 64);
    if (h == 0) {
        lsum[((size_t)ms * 16 + bh) * NTOK + nb0 + l31] = p0;
        lsum[((size_t)ms * 16 + bh) * NTOK + nb1 + l31] = p1;
    }

    // ---- O^T partial stores (bf16, FRAGMENT-MAJOR)
    short* Ob = Opart + ((size_t)ms * 2 + b) * (72 * 32 * 64 * 8);
    int nbs0 = nb0 >> 5, nbs1 = nb1 >> 5;
    int kcL = hh * 4 + (l31 >> 4);          // (k>>4) for aL (k = hh*64 + l31)
    int kcH = kcL + 2;                      // for aH (k = hh*64 + 32 + l31)
    int e = l31 & 7;
    int hs8 = ((l31 >> 3) & 1) * 32;
#pragma unroll
    for (int r = 0; r < 16; r++) {
        int ml = (r & 3) + 8 * (r >> 2) + 4 * h;
        int wi = hs8 + ml;                  // within-slot lane index
        Ob[(((size_t)nbs0 * 32 + kcL) * 64 + wi) * 8 + e] = (short)f2bf(aL0[r]);
        Ob[(((size_t)nbs0 * 32 + kcH) * 64 + wi) * 8 + e] = (short)f2bf(aH0[r]);
        Ob[(((size_t)nbs1 * 32 + kcL) * 64 + wi) * 8 + e] = (short)f2bf(aL1[r]);
        Ob[(((size_t)nbs1 * 32 + kcH) * 64 + wi) * 8 + e] = (short)f2bf(aH1[r]);
    }
}

// ---------------------------------------------------------------------------
// Combine four m-splits (bf16 frag-major partials), normalize, pack bf16 aoT
// FRAGMENT-MAJOR [b][nb=72][kc=32][lane=64][8]. Fully streaming.
// grid 1152 x 256.
// ---------------------------------------------------------------------------
__global__ __launch_bounds__(256) void combine(
    const short* __restrict__ Opart, const float* __restrict__ lsum,
    short* __restrict__ aoT)
{
    int s = blockIdx.x * 256 + threadIdx.x;       // 0..294911
    int lane = s & 63, kc = (s >> 6) & 31, nbb = s >> 11;   // nbb = b*72+nb
    int b = nbb >= 72 ? 1 : 0, nb = nbb - 72 * b;
    int l31 = lane & 31;
    int n = nb * 32 + l31;
    int hh = kc >> 2;                              // head = k/64
    float l = 0.f;
#pragma unroll
    for (int ms = 0; ms < 4; ms++)
        l += lsum[((size_t)ms * 16 + b * 8 + hh) * NTOK + n];
    float inv = 1.f / l;
    const size_t MS = 2ull * 72 * 32 * 64 * 8;     // shorts per split
    float a[8] = {0.f, 0.f, 0.f, 0.f, 0.f, 0.f, 0.f, 0.f};
#pragma unroll
    for (int ms = 0; ms < 4; ms++) {
        uint4 v = *(const uint4*)(Opart + (size_t)ms * MS + (size_t)s * 8);
        a[0] += __uint_as_float(v.x << 16);
        a[1] += __uint_as_float(v.x & 0xffff0000u);
        a[2] += __uint_as_float(v.y << 16);
        a[3] += __uint_as_float(v.y & 0xffff0000u);
        a[4] += __uint_as_float(v.z << 16);
        a[5] += __uint_as_float(v.z & 0xffff0000u);
        a[6] += __uint_as_float(v.w << 16);
        a[7] += __uint_as_float(v.w & 0xffff0000u);
    }
    unsigned b0 = f2bf(a[0] * inv) | (f2bf(a[1] * inv) << 16);
    unsigned b1 = f2bf(a[2] * inv) | (f2bf(a[3] * inv) << 16);
    unsigned b2 = f2bf(a[4] * inv) | (f2bf(a[5] * inv) << 16);
    unsigned b3 = f2bf(a[6] * inv) | (f2bf(a[7] * inv) << 16);
    *((uint4*)(aoT + (size_t)s * 8)) = make_uint4(b0, b1, b2, b3);
}

// ---------------------------------------------------------------------------
// Proj GEMM (MFMA, frag-major operands, direct store + bias). BM=64, BN=128,
// K=512. grid (18, 4, 2).
// ---------------------------------------------------------------------------
__global__ __launch_bounds__(256, 2) void gemm_proj(
    const short* __restrict__ A,     // wpb frag-major [ob=8][kc=32][64][8]
    const short* __restrict__ B,     // aoT frag-major [b][nb=72][kc=32][64][8]
    const float* __restrict__ bias, float* __restrict__ y)
{
    int b = blockIdx.z;
    int o0 = blockIdx.y * 64;
    int n0 = blockIdx.x * 128;
    int tid = threadIdx.x, wv = tid >> 6, lane = tid & 63;
    int h = lane >> 5, l31 = lane & 31;

    const short* pa = A + ((size_t)(o0 >> 5) * 32) * 512 + lane * 8;
    const short* pb = B + (((size_t)b * 72 + (n0 >> 5) + wv) * 32) * 512 + lane * 8;

    f32x16 acc0, acc1;
#pragma unroll
    for (int r = 0; r < 16; r++) { acc0[r] = 0.f; acc1[r] = 0.f; }

#pragma unroll 4
    for (int kc = 0; kc < 32; kc++) {
        bfrag a0 = *(const bfrag*)(pa + (size_t)kc * 512);
        bfrag a1 = *(const bfrag*)(pa + (size_t)(32 + kc) * 512);
        bfrag bb = *(const bfrag*)(pb + (size_t)kc * 512);
        acc0 = __builtin_amdgcn_mfma_f32_32x32x16_bf16(a0, bb, acc0, 0, 0, 0);
        acc1 = __builtin_amdgcn_mfma_f32_32x32x16_bf16(a1, bb, acc1, 0, 0, 0);
    }

    int nn = n0 + wv * 32 + l31;
#pragma unroll
    for (int r = 0; r < 16; r++) {
        int ml = (r & 3) + 8 * (r >> 2) + 4 * h;
        y[((size_t)b * CIN + o0 + ml) * NTOK + nn] = acc0[r] + bias[o0 + ml];
        y[((size_t)b * CIN + o0 + 32 + ml) * NTOK + nn] = acc1[r] + bias[o0 + 32 + ml];
    }
}

// ---------------------------------------------------------------------------
// Workspace (<= 36,446,208 B of 37,748,736):
//   [0, 18,874,368)           Opart bf16 frag-major [4][2][72][32][64][8]
//                                                          (k5 -> k6)
//   [18,874,368, 23,592,960)  vb bf16 frag-major         (k2 -> k5)
//   [23,592,960, 33,030,144)  qkt bf16 frag-major        (k2 -> k5; scaled
//                              in place k3/k4); aoT overlays (k6 -> k7)
//   [33,030,144, 33,620,000~) lsum fp32 [4][16][2304]    (k5 -> k6, over dead xT)
//   [33,030,144, 35,389,440)  xT bf16 frag-major          (k1 -> k2, dead at k5)
//   [35,389,440, 36,175,872)  wqb bf16 frag-major
//   [36,175,872, 36,438,016)  wpb bf16 frag-major
//   [36,438,016, 36,446,208)  sumsq fp32 [2048]          (k1 zero, k3 acc, k4 read)
// ---------------------------------------------------------------------------
extern "C" void kernel_launch(void* const* d_in, const int* in_sizes, int n_in,
                              void* d_out, int out_size, void* d_ws, size_t ws_size,
                              hipStream_t stream)
{
    const float* x      = (const float*)d_in[0];
    const float* w_qkv  = (const float*)d_in[1];
    const float* w_proj = (const float*)d_in[2];
    const float* b_proj = (const float*)d_in[3];
    float* y = (float*)d_out;

    short* Opart = (short*)d_ws;
    short* vb    = (short*)((char*)d_ws + 18874368);
    short* qkt   = (short*)((char*)d_ws + 23592960);
    short* aoT   = (short*)((char*)d_ws + 23592960);
    float* lsum  = (float*)((char*)d_ws + 33030144);
    short* xT    = (short*)((char*)d_ws + 33030144);
    short* wqb   = (short*)((char*)d_ws + 35389440);
    short* wpb   = (short*)((char*)d_ws + 36175872);
    float* sumsq = (float*)((char*)d_ws + 36438016);

    // k1: merged pack — xT tiles (288 blocks) + weights (256 blocks) + sumsq=0
    pack_all<<<544, 256, 0, stream>>>(w_qkv, wqb, w_proj, wpb, x, xT, sumsq);
    // k2: QKV GEMM -> unnormalized q,k bf16 frag-major (coalesced); v frag-major
    gemm_qkv<<<dim3(NTOK / 128, 1536 / 128, BATCH), 256, 0, stream>>>(
        wqb, xT, qkt, vb);
    // k3: per-row sum of squares from bf16 qkt (streaming + atomics)
    sumsq_qk<<<1152, 64, 0, stream>>>(qkt, sumsq);
    // k4: in-place normalize q (x log2e), k
    scale_qk<<<2304, 256, 0, stream>>>(qkt, sumsq);
    // k5: attention — fat waves (2 n-groups), 4-way m-split, frag-major Opart
    attn_nb<<<1152, 128, 0, stream>>>(qkt, vb, Opart, lsum);
    // k6: combine 4 splits (streaming) -> aoT frag-major bf16 (over dead qkt)
    combine<<<1152, 256, 0, stream>>>(Opart, lsum, aoT);
    // k7: proj GEMM, frag-major operands, direct store + bias
    gemm_proj<<<dim3(NTOK / 128, CIN / 64, BATCH), 256, 0, stream>>>(
        wpb, aoT, b_proj, y);
}